// Round 2
// baseline (326.024 us; speedup 1.0000x reference)
//
#include <hip/hip_runtime.h>
#include <math.h>

#define NP 1024
#define R 32
#define C 16

__device__ __forceinline__ float eluf(float x) {
    return x > 0.f ? x : expm1f(x);
}

// ---------------------------------------------------------------------------
// Kernel A: layer-1 pair pass.
// out0[a]   = sum_b r00(a,b)            (filter 0, unmasked, F=1)
// out1[a,i] = sum_b r01(a,b)*unit_i     (filter 1; unit==0 on diagonal so the
//                                        mask is implicit)
// One block per 'a', 256 threads stride 'b'. Weights are read with
// wave-uniform indices directly from global -> compiler emits s_load; FMA
// operands come from SGPRs (zero LDS/vector-load pressure in the hot loop).
// ---------------------------------------------------------------------------
__global__ __launch_bounds__(256) void k_layer1(
    const float* __restrict__ points,
    const float* __restrict__ W1, const float* __restrict__ B1,
    const float* __restrict__ W2, const float* __restrict__ B2,
    float* __restrict__ out0, float* __restrict__ out1)
{
    __shared__ float sred[4*4];
    const int tid = threadIdx.x;
    const int a = blockIdx.x;
    const float pax = points[a*3+0], pay = points[a*3+1], paz = points[a*3+2];

    float acc0 = 0.f, a1x = 0.f, a1y = 0.f, a1z = 0.f;
    for (int b = tid; b < NP; b += 256) {
        const float rx = pax - points[b*3+0];
        const float ry = pay - points[b*3+1];
        const float rz = paz - points[b*3+2];
        const float ss = rx*rx + ry*ry + rz*rz;
        const bool m0 = ss < 1e-8f;
        const float dij = m0 ? 0.f : sqrtf(ss);
        const float inv = 1.0f / sqrtf(fmaxf(ss, 1e-8f));
        const float ux = rx*inv, uy = ry*inv, uz = rz*inv;  // ==0 on diagonal
        float rbf[R];
        #pragma unroll
        for (int k = 0; k < R; k++) {
            const float t = dij - (float)k * (3.5f/31.0f);
            rbf[k] = __expf(-(32.0f/3.5f) * t * t);
        }
        float r00 = B2[0], r01 = B2[1];
        #pragma unroll 4
        for (int j = 0; j < R; j++) {
            float s0 = B1[j], s1 = B1[R+j];
            #pragma unroll
            for (int k = 0; k < R; k++) {
                s0 = fmaf(rbf[k], W1[k*R + j], s0);          // s_load operand
                s1 = fmaf(rbf[k], W1[R*R + k*R + j], s1);
            }
            r00 = fmaf(fmaxf(s0, 0.f), W2[j],   r00);
            r01 = fmaf(fmaxf(s1, 0.f), W2[R+j], r01);
        }
        acc0 += r00;
        a1x = fmaf(r01, ux, a1x);   // diagonal lane: u==0 -> no contribution
        a1y = fmaf(r01, uy, a1y);
        a1z = fmaf(r01, uz, a1z);
    }
    #pragma unroll
    for (int off = 32; off > 0; off >>= 1) {
        acc0 += __shfl_down(acc0, off);
        a1x  += __shfl_down(a1x,  off);
        a1y  += __shfl_down(a1y,  off);
        a1z  += __shfl_down(a1z,  off);
    }
    const int lane = tid & 63, wv = tid >> 6;
    if (lane == 0) {
        sred[wv*4+0] = acc0; sred[wv*4+1] = a1x;
        sred[wv*4+2] = a1y;  sred[wv*4+3] = a1z;
    }
    __syncthreads();
    if (tid == 0) {
        float t0 = 0.f, t1 = 0.f, t2 = 0.f, t3 = 0.f;
        for (int w = 0; w < 4; w++) {
            t0 += sred[w*4+0]; t1 += sred[w*4+1];
            t2 += sred[w*4+2]; t3 += sred[w*4+3];
        }
        out0[a] = t0;
        out1[a*3+0] = t1; out1[a*3+1] = t2; out1[a*3+2] = t3;
    }
}

// ---------------------------------------------------------------------------
// Kernel B: per-point layer-1 features, written TRANSPOSED for coalesced
// reads in k_layer2:  x0T[f][b], x1T[i][f][b].
// ---------------------------------------------------------------------------
__global__ __launch_bounds__(256) void k_point1(
    const float* __restrict__ out0, const float* __restrict__ out1,
    const float* __restrict__ si0_w, const float* __restrict__ si0_b,
    const float* __restrict__ si1_w, const float* __restrict__ nl_b,
    float* __restrict__ x0T, float* __restrict__ x1T)
{
    const int b = blockIdx.x*256 + threadIdx.x;
    if (b >= NP) return;
    const float o0 = out0[b];
    const float o1x = out1[b*3+0], o1y = out1[b*3+1], o1z = out1[b*3+2];
    #pragma unroll
    for (int g = 0; g < C; g++) {
        x0T[g*NP + b] = eluf(fmaf(o0, si0_w[g], si0_b[g]));
        const float w = si1_w[g];
        const float tx = o1x*w, ty = o1y*w, tz = o1z*w;
        const float n = sqrtf(fmaxf(tx*tx + ty*ty + tz*tz, 1e-8f));
        const float sc = eluf(n + nl_b[g]) / n;
        x1T[(0*C+g)*NP + b] = tx*sc;
        x1T[(1*C+g)*NP + b] = ty*sc;
        x1T[(2*C+g)*NP + b] = tz*sc;
    }
}

// ---------------------------------------------------------------------------
// Kernel C: layer-2 pair pass. ONLY filters 0 (0x0->0) and 2 (1x1->0) are
// live — the degree-1 layer-2 outputs are dead code in the reference.
// c00[a,f] = sum_b rad0(a,b,f) * x0[b,f]
// c10[a,f] = sum_b rad2(a,b,f) * dot(unit(a,b), x1[b,f,:])   (unit=0 on diag)
// Weights via wave-uniform global reads (s_load); features via coalesced
// vector loads from the transposed layouts.
// ---------------------------------------------------------------------------
__global__ __launch_bounds__(256) void k_layer2(
    const float* __restrict__ points,
    const float* __restrict__ W1, const float* __restrict__ B1,
    const float* __restrict__ W2, const float* __restrict__ B2,
    const float* __restrict__ x0T, const float* __restrict__ x1T,
    float* __restrict__ c00, float* __restrict__ c10)
{
    __shared__ float sred[4*2*C];
    const int tid = threadIdx.x;
    const int a = blockIdx.x;
    const float pax = points[a*3+0], pay = points[a*3+1], paz = points[a*3+2];

    float acc00[C], acc10[C];
    #pragma unroll
    for (int f = 0; f < C; f++) { acc00[f] = 0.f; acc10[f] = 0.f; }

    for (int b = tid; b < NP; b += 256) {
        const float rx = pax - points[b*3+0];
        const float ry = pay - points[b*3+1];
        const float rz = paz - points[b*3+2];
        const float ss = rx*rx + ry*ry + rz*rz;
        const bool m0 = ss < 1e-8f;
        const float dij = m0 ? 0.f : sqrtf(ss);
        const float inv = 1.0f / sqrtf(fmaxf(ss, 1e-8f));
        const float ux = rx*inv, uy = ry*inv, uz = rz*inv;  // ==0 on diagonal

        // issue feature loads early; they drain on the VMEM pipe while the
        // FMA blocks below execute
        float xv[C], ud[C];
        #pragma unroll
        for (int f = 0; f < C; f++) xv[f] = x0T[f*NP + b];
        #pragma unroll
        for (int f = 0; f < C; f++) {
            const float vx = x1T[(0*C+f)*NP + b];
            const float vy = x1T[(1*C+f)*NP + b];
            const float vz = x1T[(2*C+f)*NP + b];
            ud[f] = ux*vx + uy*vy + uz*vz;
        }

        float rbf[R];
        #pragma unroll
        for (int k = 0; k < R; k++) {
            const float t = dij - (float)k * (3.5f/31.0f);
            rbf[k] = __expf(-(32.0f/3.5f) * t * t);
        }

        float h[R];
        // filter 0 (index 0 in W1/B1/W2/B2), unmasked
        #pragma unroll 4
        for (int j = 0; j < R; j++) {
            float s = B1[j];
            #pragma unroll
            for (int k = 0; k < R; k++) s = fmaf(rbf[k], W1[k*R + j], s);
            h[j] = fmaxf(s, 0.f);
        }
        #pragma unroll 4
        for (int f = 0; f < C; f++) {
            float r = B2[f];
            #pragma unroll
            for (int j = 0; j < R; j++) r = fmaf(h[j], W2[j*C + f], r);
            acc00[f] = fmaf(r, xv[f], acc00[f]);
        }
        // filter 2 (index 2), mask implicit via unit==0 on diagonal
        #pragma unroll 4
        for (int j = 0; j < R; j++) {
            float s = B1[2*R + j];
            #pragma unroll
            for (int k = 0; k < R; k++) s = fmaf(rbf[k], W1[2*R*R + k*R + j], s);
            h[j] = fmaxf(s, 0.f);
        }
        #pragma unroll 4
        for (int f = 0; f < C; f++) {
            float r = B2[2*C + f];
            #pragma unroll
            for (int j = 0; j < R; j++) r = fmaf(h[j], W2[2*R*C + j*C + f], r);
            acc10[f] = fmaf(r, ud[f], acc10[f]);
        }
    }
    #pragma unroll
    for (int off = 32; off > 0; off >>= 1) {
        #pragma unroll
        for (int f = 0; f < C; f++) {
            acc00[f] += __shfl_down(acc00[f], off);
            acc10[f] += __shfl_down(acc10[f], off);
        }
    }
    const int lane = tid & 63, wv = tid >> 6;
    if (lane == 0) {
        #pragma unroll
        for (int f = 0; f < C; f++) {
            sred[wv*2*C + f]     = acc00[f];
            sred[wv*2*C + C + f] = acc10[f];
        }
    }
    __syncthreads();
    if (tid < 2*C) {
        const float s = sred[tid] + sred[2*C + tid] + sred[4*C + tid] + sred[6*C + tid];
        if (tid < C) c00[a*C + tid] = s;
        else         c10[a*C + (tid - C)] = s;
    }
}

// ---------------------------------------------------------------------------
// Kernel D1: per-point layer-2 degree-0 features + partial mean pool.
// ---------------------------------------------------------------------------
__global__ __launch_bounds__(256) void k_readout1(
    const float* __restrict__ c00, const float* __restrict__ c10,
    const float* __restrict__ si0_w, const float* __restrict__ si0_b,
    float* __restrict__ partial)
{
    __shared__ float sred[4*C];
    const int tid = threadIdx.x;
    const int a = blockIdx.x*256 + tid;
    float v00[C], v10[C];
    #pragma unroll
    for (int f = 0; f < C; f++) { v00[f] = c00[a*C+f]; v10[f] = c10[a*C+f]; }
    float xg[C];
    #pragma unroll
    for (int g = 0; g < C; g++) {
        float s = si0_b[g];
        #pragma unroll
        for (int f = 0; f < C; f++) s = fmaf(v00[f], si0_w[g*2*C + f], s);
        #pragma unroll
        for (int f = 0; f < C; f++) s = fmaf(v10[f], si0_w[g*2*C + C + f], s);
        xg[g] = eluf(s);
    }
    #pragma unroll
    for (int off = 32; off > 0; off >>= 1) {
        #pragma unroll
        for (int g = 0; g < C; g++) xg[g] += __shfl_down(xg[g], off);
    }
    const int lane = tid & 63, wv = tid >> 6;
    if (lane == 0) {
        #pragma unroll
        for (int g = 0; g < C; g++) sred[wv*C + g] = xg[g];
    }
    __syncthreads();
    if (tid < C) {
        partial[blockIdx.x*C + tid] =
            sred[tid] + sred[C + tid] + sred[2*C + tid] + sred[3*C + tid];
    }
}

// ---------------------------------------------------------------------------
// Kernel D2: final FC.
// ---------------------------------------------------------------------------
__global__ void k_readout2(const float* __restrict__ partial,
                           const float* __restrict__ fc_w,
                           const float* __restrict__ fc_b,
                           float* __restrict__ out)
{
    const int o = threadIdx.x;
    if (o < 8) {
        float s = fc_b[o];
        #pragma unroll
        for (int g = 0; g < C; g++) {
            const float m = (partial[g] + partial[C+g] + partial[2*C+g] + partial[3*C+g])
                            * (1.0f / (float)NP);
            s = fmaf(m, fc_w[g*8 + o], s);
        }
        out[o] = s;
    }
}

extern "C" void kernel_launch(void* const* d_in, const int* in_sizes, int n_in,
                              void* d_out, int out_size, void* d_ws, size_t ws_size,
                              hipStream_t stream)
{
    (void)in_sizes; (void)n_in; (void)out_size; (void)ws_size;
    const float* points   = (const float*)d_in[0];
    const float* l1_W1    = (const float*)d_in[1];
    const float* l1_B1    = (const float*)d_in[2];
    const float* l1_W2    = (const float*)d_in[3];
    const float* l1_B2    = (const float*)d_in[4];
    const float* l1_si0_w = (const float*)d_in[5];
    const float* l1_si0_b = (const float*)d_in[6];
    const float* l1_si1_w = (const float*)d_in[7];
    const float* l1_nl_b  = (const float*)d_in[8];
    const float* l2_W1    = (const float*)d_in[9];
    const float* l2_B1    = (const float*)d_in[10];
    const float* l2_W2    = (const float*)d_in[11];
    const float* l2_B2    = (const float*)d_in[12];
    const float* l2_si0_w = (const float*)d_in[13];
    const float* l2_si0_b = (const float*)d_in[14];
    // d_in[15] l2_si1_w, d_in[16] l2_nl_b: dead code in the reference readout
    const float* fc_w     = (const float*)d_in[17];
    const float* fc_b     = (const float*)d_in[18];

    float* ws      = (float*)d_ws;
    float* out0    = ws;                    // NP
    float* out1    = out0 + NP;             // NP*3
    float* x0T     = out1 + NP*3;           // C*NP
    float* x1T     = x0T + C*NP;            // 3*C*NP
    float* c00     = x1T + 3*C*NP;          // NP*C
    float* c10     = c00 + NP*C;            // NP*C
    float* partial = c10 + NP*C;            // 4*C

    k_layer1<<<NP, 256, 0, stream>>>(points, l1_W1, l1_B1, l1_W2, l1_B2, out0, out1);
    k_point1<<<NP/256, 256, 0, stream>>>(out0, out1, l1_si0_w, l1_si0_b, l1_si1_w, l1_nl_b, x0T, x1T);
    k_layer2<<<NP, 256, 0, stream>>>(points, l2_W1, l2_B1, l2_W2, l2_B2, x0T, x1T, c00, c10);
    k_readout1<<<NP/256, 256, 0, stream>>>(c00, c10, l2_si0_w, l2_si0_b, partial);
    k_readout2<<<1, 64, 0, stream>>>(partial, fc_w, fc_b, (float*)d_out);
}

// Round 3
// 187.673 us; speedup vs baseline: 1.7372x; 1.7372x over previous
//
#include <hip/hip_runtime.h>
#include <hip/hip_bf16.h>
#include <math.h>

#define NP 1024
#define R 32
#define C 16
#define GAMMA (32.0f/3.5f)
#define DC (3.5f/31.0f)

typedef __attribute__((ext_vector_type(8))) short bf16x8;
typedef __attribute__((ext_vector_type(4))) float f32x4;

__device__ __forceinline__ short tobf(float x){
    __hip_bfloat16 h = __float2bfloat16(x);
    return __builtin_bit_cast(short, h);
}
__device__ __forceinline__ float frombf(short s){
    __hip_bfloat16 h = __builtin_bit_cast(__hip_bfloat16, s);
    return __bfloat162float(h);
}
__device__ __forceinline__ float eluf(float x){ return x > 0.f ? x : expm1f(x); }

__device__ __forceinline__ f32x4 mfma16(bf16x8 a, bf16x8 b, f32x4 c){
    return __builtin_amdgcn_mfma_f32_16x16x32_bf16(a, b, c, 0, 0, 0);
}

// B-operand fragment (n = lane&15 handled by caller via 'n'): element jj of the
// frag is B[k = q*8+jj][n]. Split into bf16 hi + lo so weight rounding error is
// ~fp32-level (2 MFMAs instead of 1).
template<int STRIDE>
__device__ __forceinline__ void load_bfrag(const float* __restrict__ src, int q, int n,
                                           bf16x8& hi, bf16x8& lo){
    #pragma unroll
    for (int jj = 0; jj < 8; jj++){
        const float w = src[(q*8+jj)*STRIDE + n];
        const short h = tobf(w);
        hi[jj] = h;
        lo[jj] = tobf(w - frombf(h));
    }
}

// ---------------------------------------------------------------------------
// Layer 1 (MFMA): block per 'a'. Wave w handles M-tile rows b_local=w*16+0..15
// per b-tile of 64. GEMM1 only (N=32, 2 N-tiles, hi+lo = 4 MFMA per filter).
// filter0: out0[a] = sum_j w2_0[j]*S0[j] + NP*B2_0,  S0[j]=sum_b relu-h0[b,j]
// filter1: out1[a,i] = sum_j w2_1[j]*T[j,i] + B2_1*U_i,
//          T[j,i]=sum_b relu-h1[b,j]*u_i(a,b), U_i=sum_b u_i  (u=0 on diag)
// ---------------------------------------------------------------------------
__global__ __launch_bounds__(256) void k_layer1(
    const float* __restrict__ points,
    const float* __restrict__ W1, const float* __restrict__ B1,
    const float* __restrict__ W2, const float* __restrict__ B2,
    float* __restrict__ out0, float* __restrict__ out1)
{
    __shared__ float sDij[64];
    __shared__ float sU[64*4];
    __shared__ float sS0[4][32];
    __shared__ float sT[4][32][3];
    __shared__ float sUred[3];

    const int tid  = threadIdx.x;
    const int lane = tid & 63;
    const int wv   = tid >> 6;
    const int l16  = lane & 15;
    const int q    = lane >> 4;
    const int a    = blockIdx.x;
    const float pax = points[a*3+0], pay = points[a*3+1], paz = points[a*3+2];

    bf16x8 w1hi[2][2], w1lo[2][2];
    float  b1v[2][2];
    #pragma unroll
    for (int fi = 0; fi < 2; fi++){
        #pragma unroll
        for (int nt = 0; nt < 2; nt++){
            load_bfrag<R>(W1 + fi*R*R, q, nt*16 + l16, w1hi[fi][nt], w1lo[fi][nt]);
            b1v[fi][nt] = B1[fi*R + nt*16 + l16];
        }
    }

    float s0acc0 = 0.f, s0acc1 = 0.f;   // S0 partial, j = nt*16 + l16
    float T[2][3] = {};                 // T partial  [nt][i]
    float upx = 0.f, upy = 0.f, upz = 0.f;

    for (int bt = 0; bt < 16; bt++){
        __syncthreads();
        if (tid < 64){
            const int b = bt*64 + tid;
            const float rx = pax - points[b*3+0];
            const float ry = pay - points[b*3+1];
            const float rz = paz - points[b*3+2];
            const float ss = rx*rx + ry*ry + rz*rz;
            const float dij = sqrtf(ss);
            const float inv = 1.0f / sqrtf(fmaxf(ss, 1e-8f));
            const float ux = rx*inv, uy = ry*inv, uz = rz*inv;  // 0 on diagonal
            sDij[tid] = dij;
            sU[tid*4+0] = ux; sU[tid*4+1] = uy; sU[tid*4+2] = uz;
            upx += ux; upy += uy; upz += uz;
        }
        __syncthreads();

        // A fragment: rows m=l16 -> b = bt*64 + wv*16 + l16; k = q*8+jj
        const float dij = sDij[wv*16 + l16];
        bf16x8 afrag;
        #pragma unroll
        for (int jj = 0; jj < 8; jj++){
            const float t = dij - (float)(q*8+jj)*DC;
            afrag[jj] = tobf(__expf(-GAMMA*t*t));
        }

        // filter 0: GEMM1 + row-sum into S0
        #pragma unroll
        for (int nt = 0; nt < 2; nt++){
            f32x4 c = {b1v[0][nt], b1v[0][nt], b1v[0][nt], b1v[0][nt]};
            c = mfma16(afrag, w1hi[0][nt], c);
            c = mfma16(afrag, w1lo[0][nt], c);
            const float s = fmaxf(c[0],0.f)+fmaxf(c[1],0.f)+fmaxf(c[2],0.f)+fmaxf(c[3],0.f);
            if (nt == 0) s0acc0 += s; else s0acc1 += s;
        }
        // filter 1: GEMM1 + u-weighted row-sum into T
        #pragma unroll
        for (int nt = 0; nt < 2; nt++){
            f32x4 c = {b1v[1][nt], b1v[1][nt], b1v[1][nt], b1v[1][nt]};
            c = mfma16(afrag, w1hi[1][nt], c);
            c = mfma16(afrag, w1lo[1][nt], c);
            #pragma unroll
            for (int r4 = 0; r4 < 4; r4++){
                const float h = fmaxf(c[r4], 0.f);
                const int bl = wv*16 + q*4 + r4;           // C rows = quad*4+reg
                T[nt][0] = fmaf(h, sU[bl*4+0], T[nt][0]);
                T[nt][1] = fmaf(h, sU[bl*4+1], T[nt][1]);
                T[nt][2] = fmaf(h, sU[bl*4+2], T[nt][2]);
            }
        }
    }

    // cross-quad reduce (rows live in quads)
    s0acc0 += __shfl_down(s0acc0, 32, 64); s0acc0 += __shfl_down(s0acc0, 16, 64);
    s0acc1 += __shfl_down(s0acc1, 32, 64); s0acc1 += __shfl_down(s0acc1, 16, 64);
    #pragma unroll
    for (int nt = 0; nt < 2; nt++)
        #pragma unroll
        for (int i = 0; i < 3; i++){
            T[nt][i] += __shfl_down(T[nt][i], 32, 64);
            T[nt][i] += __shfl_down(T[nt][i], 16, 64);
        }
    if (lane < 16){
        sS0[wv][lane]      = s0acc0;
        sS0[wv][16 + lane] = s0acc1;
        #pragma unroll
        for (int i = 0; i < 3; i++){
            sT[wv][lane][i]      = T[0][i];
            sT[wv][16 + lane][i] = T[1][i];
        }
    }
    if (wv == 0){
        #pragma unroll
        for (int off = 32; off > 0; off >>= 1){
            upx += __shfl_down(upx, off, 64);
            upy += __shfl_down(upy, off, 64);
            upz += __shfl_down(upz, off, 64);
        }
        if (lane == 0){ sUred[0] = upx; sUred[1] = upy; sUred[2] = upz; }
    }
    __syncthreads();
    if (tid == 0){
        float o0 = 0.f;
        for (int j = 0; j < R; j++){
            const float S = sS0[0][j] + sS0[1][j] + sS0[2][j] + sS0[3][j];
            o0 = fmaf(S, W2[j], o0);
        }
        out0[a] = o0 + (float)NP * B2[0];
        for (int i = 0; i < 3; i++){
            float t = 0.f;
            for (int j = 0; j < R; j++){
                const float Tj = sT[0][j][i] + sT[1][j][i] + sT[2][j][i] + sT[3][j][i];
                t = fmaf(Tj, W2[R + j], t);
            }
            out1[a*3+i] = t + B2[1] * sUred[i];
        }
    }
}

// ---------------------------------------------------------------------------
// Per-point layer-1 features, natural layouts x0[b][f], x1[b][f][i].
// ---------------------------------------------------------------------------
__global__ __launch_bounds__(256) void k_point1(
    const float* __restrict__ out0, const float* __restrict__ out1,
    const float* __restrict__ si0_w, const float* __restrict__ si0_b,
    const float* __restrict__ si1_w, const float* __restrict__ nl_b,
    float* __restrict__ x0g, float* __restrict__ x1g)
{
    const int b = blockIdx.x*256 + threadIdx.x;
    if (b >= NP) return;
    const float o0 = out0[b];
    const float o1x = out1[b*3+0], o1y = out1[b*3+1], o1z = out1[b*3+2];
    #pragma unroll
    for (int g = 0; g < C; g++){
        x0g[b*C+g] = eluf(fmaf(o0, si0_w[g], si0_b[g]));
        const float w = si1_w[g];
        const float tx = o1x*w, ty = o1y*w, tz = o1z*w;
        const float n = sqrtf(fmaxf(tx*tx + ty*ty + tz*tz, 1e-8f));
        const float sc = eluf(n + nl_b[g]) / n;
        x1g[(b*C+g)*3+0] = tx*sc;
        x1g[(b*C+g)*3+1] = ty*sc;
        x1g[(b*C+g)*3+2] = tz*sc;
    }
}

// ---------------------------------------------------------------------------
// Layer 2 (MFMA): block per 'a'. Only live filters 0 (0x0->0) and 2 (1x1->0).
// Per M-tile per filter: GEMM1 (2 Nt x hi/lo = 4 MFMA) -> relu -> LDS
// round-trip (C-layout -> A-layout) -> GEMM2 (hi/lo = 2 MFMA) -> epilogue
// multiply by sX0 (f0) or precomputed sUD (f2) and row-sum over b.
// ---------------------------------------------------------------------------
__global__ __launch_bounds__(256) void k_layer2(
    const float* __restrict__ points,
    const float* __restrict__ W1, const float* __restrict__ B1,
    const float* __restrict__ W2, const float* __restrict__ B2,
    const float* __restrict__ x0g, const float* __restrict__ x1g,
    float* __restrict__ c00, float* __restrict__ c10)
{
    __shared__ float sDij[64];
    __shared__ float sU[64*4];
    __shared__ float sX0[64*17];
    __shared__ float sUD[64*17];
    __shared__ __align__(16) short sH[4*16*40];   // per-wave 16 rows x stride 40
    __shared__ float sRed[4][2][16];

    const int tid  = threadIdx.x;
    const int lane = tid & 63;
    const int wv   = tid >> 6;
    const int l16  = lane & 15;
    const int q    = lane >> 4;
    const int a    = blockIdx.x;
    const float pax = points[a*3+0], pay = points[a*3+1], paz = points[a*3+2];

    bf16x8 w1hi[2][2], w1lo[2][2], w2hi[2], w2lo[2];
    float  b1v[2][2], b2v[2];
    #pragma unroll
    for (int fi = 0; fi < 2; fi++){
        const int fx = (fi == 0) ? 0 : 2;
        #pragma unroll
        for (int nt = 0; nt < 2; nt++){
            load_bfrag<R>(W1 + fx*R*R, q, nt*16 + l16, w1hi[fi][nt], w1lo[fi][nt]);
            b1v[fi][nt] = B1[fx*R + nt*16 + l16];
        }
        load_bfrag<C>(W2 + fx*R*C, q, l16, w2hi[fi], w2lo[fi]);
        b2v[fi] = B2[fx*C + l16];
    }

    float acc0 = 0.f, acc1 = 0.f;       // partial c00/c10 for f = l16
    short* sHw = sH + wv*16*40;

    for (int bt = 0; bt < 16; bt++){
        __syncthreads();
        if (tid < 64){
            const int b = bt*64 + tid;
            const float rx = pax - points[b*3+0];
            const float ry = pay - points[b*3+1];
            const float rz = paz - points[b*3+2];
            const float ss = rx*rx + ry*ry + rz*rz;
            sDij[tid] = sqrtf(ss);
            const float inv = 1.0f / sqrtf(fmaxf(ss, 1e-8f));
            sU[tid*4+0] = rx*inv; sU[tid*4+1] = ry*inv; sU[tid*4+2] = rz*inv;
        }
        #pragma unroll
        for (int e = 0; e < 4; e++){
            const int idx = tid + 256*e;
            const int bl = idx >> 4, f = idx & 15;
            sX0[bl*17+f] = x0g[(bt*64+bl)*C + f];
        }
        __syncthreads();
        #pragma unroll
        for (int e = 0; e < 4; e++){
            const int idx = tid + 256*e;
            const int bl = idx >> 4, f = idx & 15;
            const float* xp = x1g + (size_t)((bt*64+bl)*C + f)*3;
            sUD[bl*17+f] = sU[bl*4+0]*xp[0] + sU[bl*4+1]*xp[1] + sU[bl*4+2]*xp[2];
        }
        __syncthreads();

        // A-frag: rows m=l16 -> b_local = wv*16+l16
        const float dij = sDij[wv*16 + l16];
        bf16x8 afrag;
        #pragma unroll
        for (int jj = 0; jj < 8; jj++){
            const float t = dij - (float)(q*8+jj)*DC;
            afrag[jj] = tobf(__expf(-GAMMA*t*t));
        }

        #pragma unroll
        for (int fi = 0; fi < 2; fi++){
            f32x4 c0 = {b1v[fi][0], b1v[fi][0], b1v[fi][0], b1v[fi][0]};
            c0 = mfma16(afrag, w1hi[fi][0], c0);
            c0 = mfma16(afrag, w1lo[fi][0], c0);
            f32x4 c1 = {b1v[fi][1], b1v[fi][1], b1v[fi][1], b1v[fi][1]};
            c1 = mfma16(afrag, w1hi[fi][1], c1);
            c1 = mfma16(afrag, w1lo[fi][1], c1);
            // H (relu) -> LDS, C-layout write (rows q*4+r, col l16 / 16+l16)
            #pragma unroll
            for (int r4 = 0; r4 < 4; r4++){
                sHw[(q*4+r4)*40 + l16]      = tobf(fmaxf(c0[r4], 0.f));
                sHw[(q*4+r4)*40 + 16 + l16] = tobf(fmaxf(c1[r4], 0.f));
            }
            asm volatile("s_waitcnt lgkmcnt(0)" ::: "memory");
            // A-layout read: row m=l16, k = q*8..q*8+7 (16B aligned, stride 80B)
            const bf16x8 hf = *(const bf16x8*)(sHw + l16*40 + q*8);
            f32x4 d = {0.f, 0.f, 0.f, 0.f};
            d = mfma16(hf, w2hi[fi], d);
            d = mfma16(hf, w2lo[fi], d);
            const float* mlt = (fi == 0) ? sX0 : sUD;
            #pragma unroll
            for (int r4 = 0; r4 < 4; r4++){
                const float m = mlt[(wv*16 + q*4 + r4)*17 + l16];
                const float v = d[r4] + b2v[fi];
                if (fi == 0) acc0 = fmaf(v, m, acc0);
                else         acc1 = fmaf(v, m, acc1);
            }
        }
    }

    acc0 += __shfl_down(acc0, 32, 64); acc0 += __shfl_down(acc0, 16, 64);
    acc1 += __shfl_down(acc1, 32, 64); acc1 += __shfl_down(acc1, 16, 64);
    if (lane < 16){ sRed[wv][0][lane] = acc0; sRed[wv][1][lane] = acc1; }
    __syncthreads();
    if (tid < 16)
        c00[a*C + tid] = sRed[0][0][tid] + sRed[1][0][tid] + sRed[2][0][tid] + sRed[3][0][tid];
    else if (tid < 32){
        const int f = tid - 16;
        c10[a*C + f] = sRed[0][1][f] + sRed[1][1][f] + sRed[2][1][f] + sRed[3][1][f];
    }
}

// ---------------------------------------------------------------------------
// Readout stage 1: per-point layer-2 degree-0 features + partial mean pool.
// ---------------------------------------------------------------------------
__global__ __launch_bounds__(256) void k_readout1(
    const float* __restrict__ c00, const float* __restrict__ c10,
    const float* __restrict__ si0_w, const float* __restrict__ si0_b,
    float* __restrict__ partial)
{
    __shared__ float sred[4*C];
    const int tid = threadIdx.x;
    const int a = blockIdx.x*256 + tid;
    float v00[C], v10[C];
    #pragma unroll
    for (int f = 0; f < C; f++){ v00[f] = c00[a*C+f]; v10[f] = c10[a*C+f]; }
    float xg[C];
    #pragma unroll
    for (int g = 0; g < C; g++){
        float s = si0_b[g];
        #pragma unroll
        for (int f = 0; f < C; f++) s = fmaf(v00[f], si0_w[g*2*C + f], s);
        #pragma unroll
        for (int f = 0; f < C; f++) s = fmaf(v10[f], si0_w[g*2*C + C + f], s);
        xg[g] = eluf(s);
    }
    #pragma unroll
    for (int off = 32; off > 0; off >>= 1){
        #pragma unroll
        for (int g = 0; g < C; g++) xg[g] += __shfl_down(xg[g], off, 64);
    }
    const int lane = tid & 63, wv = tid >> 6;
    if (lane == 0){
        #pragma unroll
        for (int g = 0; g < C; g++) sred[wv*C + g] = xg[g];
    }
    __syncthreads();
    if (tid < C)
        partial[blockIdx.x*C + tid] =
            sred[tid] + sred[C + tid] + sred[2*C + tid] + sred[3*C + tid];
}

__global__ void k_readout2(const float* __restrict__ partial,
                           const float* __restrict__ fc_w,
                           const float* __restrict__ fc_b,
                           float* __restrict__ out)
{
    const int o = threadIdx.x;
    if (o < 8){
        float s = fc_b[o];
        #pragma unroll
        for (int g = 0; g < C; g++){
            const float m = (partial[g] + partial[C+g] + partial[2*C+g] + partial[3*C+g])
                            * (1.0f / (float)NP);
            s = fmaf(m, fc_w[g*8 + o], s);
        }
        out[o] = s;
    }
}

extern "C" void kernel_launch(void* const* d_in, const int* in_sizes, int n_in,
                              void* d_out, int out_size, void* d_ws, size_t ws_size,
                              hipStream_t stream)
{
    (void)in_sizes; (void)n_in; (void)out_size; (void)ws_size;
    const float* points   = (const float*)d_in[0];
    const float* l1_W1    = (const float*)d_in[1];
    const float* l1_B1    = (const float*)d_in[2];
    const float* l1_W2    = (const float*)d_in[3];
    const float* l1_B2    = (const float*)d_in[4];
    const float* l1_si0_w = (const float*)d_in[5];
    const float* l1_si0_b = (const float*)d_in[6];
    const float* l1_si1_w = (const float*)d_in[7];
    const float* l1_nl_b  = (const float*)d_in[8];
    const float* l2_W1    = (const float*)d_in[9];
    const float* l2_B1    = (const float*)d_in[10];
    const float* l2_W2    = (const float*)d_in[11];
    const float* l2_B2    = (const float*)d_in[12];
    const float* l2_si0_w = (const float*)d_in[13];
    const float* l2_si0_b = (const float*)d_in[14];
    // d_in[15] l2_si1_w, d_in[16] l2_nl_b: dead code in the reference readout
    const float* fc_w     = (const float*)d_in[17];
    const float* fc_b     = (const float*)d_in[18];

    float* ws      = (float*)d_ws;
    float* out0    = ws;                    // NP
    float* out1    = out0 + NP;             // NP*3
    float* x0g     = out1 + NP*3;           // NP*C
    float* x1g     = x0g + NP*C;            // NP*C*3
    float* c00     = x1g + NP*C*3;          // NP*C
    float* c10     = c00 + NP*C;            // NP*C
    float* partial = c10 + NP*C;            // 4*C

    k_layer1<<<NP, 256, 0, stream>>>(points, l1_W1, l1_B1, l1_W2, l1_B2, out0, out1);
    k_point1<<<NP/256, 256, 0, stream>>>(out0, out1, l1_si0_w, l1_si0_b, l1_si1_w, l1_nl_b, x0g, x1g);
    k_layer2<<<NP, 256, 0, stream>>>(points, l2_W1, l2_B1, l2_W2, l2_B2, x0g, x1g, c00, c10);
    k_readout1<<<NP/256, 256, 0, stream>>>(c00, c10, l2_si0_w, l2_si0_b, partial);
    k_readout2<<<1, 64, 0, stream>>>(partial, fc_w, fc_b, (float*)d_out);
}

// Round 5
// 173.417 us; speedup vs baseline: 1.8800x; 1.0822x over previous
//
#include <hip/hip_runtime.h>
#include <hip/hip_bf16.h>
#include <math.h>

#define NP 1024
#define R 32
#define C 16
#define GAMMA (32.0f/3.5f)
#define DC (3.5f/31.0f)

typedef __attribute__((ext_vector_type(8))) short bf16x8;
typedef __attribute__((ext_vector_type(4))) float f32x4;

__device__ __forceinline__ short tobf(float x){
    __hip_bfloat16 h = __float2bfloat16(x);
    return __builtin_bit_cast(short, h);
}
__device__ __forceinline__ float frombf(short s){
    __hip_bfloat16 h = __builtin_bit_cast(__hip_bfloat16, s);
    return __bfloat162float(h);
}
__device__ __forceinline__ unsigned pack2bf(float a, float b){
    const unsigned lo = (unsigned short)tobf(a);
    const unsigned hi = (unsigned short)tobf(b);
    return lo | (hi << 16);
}
__device__ __forceinline__ float eluf(float x){ return x > 0.f ? x : expm1f(x); }

__device__ __forceinline__ f32x4 mfma16(bf16x8 a, bf16x8 b, f32x4 c){
    return __builtin_amdgcn_mfma_f32_16x16x32_bf16(a, b, c, 0, 0, 0);
}

// B-operand fragment: element jj = src[(q*8+jj)*STRIDE + n]. bf16 hi+lo split
// keeps weight rounding at ~fp32 level (2 MFMAs per GEMM).
template<int STRIDE>
__device__ __forceinline__ void load_bfrag(const float* __restrict__ src, int q, int n,
                                           bf16x8& hi, bf16x8& lo){
    #pragma unroll
    for (int jj = 0; jj < 8; jj++){
        const float w = src[(q*8+jj)*STRIDE + n];
        const short h = tobf(w);
        hi[jj] = h;
        lo[jj] = tobf(w - frombf(h));
    }
}

// ---------------------------------------------------------------------------
// Layer 1 (MFMA, BARRIER-FREE K-loop): block per 'a', wave handles 16 b-rows
// per b-tile of 64. Per-lane geometry (row l16); u for epilogue rows via
// width-16 shuffles; no LDS staging, no __syncthreads until final reduce.
// out0[a]   = sum_j W2_0[j]*S0[j] + NP*B2_0,   S0[j] = sum_b relu_h0[b,j]
// out1[a,i] = sum_j W2_1[j]*T[j,i] + B2_1*U_i, T[j,i]= sum_b relu_h1[b,j]*u_i
// ---------------------------------------------------------------------------
__global__ __launch_bounds__(256) void k_layer1(
    const float* __restrict__ points,
    const float* __restrict__ W1, const float* __restrict__ B1,
    const float* __restrict__ W2, const float* __restrict__ B2,
    float* __restrict__ out0, float* __restrict__ out1)
{
    __shared__ float sS0[4][32];
    __shared__ float sT[4][32][3];
    __shared__ float sUp[4][3];

    const int tid  = threadIdx.x;
    const int lane = tid & 63;
    const int wv   = tid >> 6;
    const int l16  = lane & 15;
    const int q    = lane >> 4;
    const int a    = blockIdx.x;
    const float pax = points[a*3+0], pay = points[a*3+1], paz = points[a*3+2];

    bf16x8 w1hi[2][2], w1lo[2][2];
    float  b1v[2][2];
    #pragma unroll
    for (int fi = 0; fi < 2; fi++)
        #pragma unroll
        for (int nt = 0; nt < 2; nt++){
            load_bfrag<R>(W1 + fi*R*R, q, nt*16 + l16, w1hi[fi][nt], w1lo[fi][nt]);
            b1v[fi][nt] = B1[fi*R + nt*16 + l16];
        }

    float s0a[2] = {0.f, 0.f};
    float T[2][3] = {};
    float upx = 0.f, upy = 0.f, upz = 0.f;

    for (int bt = 0; bt < 16; bt++){
        const int bA = bt*64 + wv*16 + l16;
        const float rx = pax - points[bA*3+0];
        const float ry = pay - points[bA*3+1];
        const float rz = paz - points[bA*3+2];
        const float ss = rx*rx + ry*ry + rz*rz;
        const float dij = sqrtf(ss);
        const float inv = 1.0f / sqrtf(fmaxf(ss, 1e-8f));
        const float ux = rx*inv, uy = ry*inv, uz = rz*inv;  // ==0 on diagonal
        upx += ux; upy += uy; upz += uz;                    // 4x overcount, /4 later

        bf16x8 afrag;
        #pragma unroll
        for (int jj = 0; jj < 8; jj++){
            const float t = dij - (float)(q*8+jj)*DC;
            afrag[jj] = tobf(__expf(-GAMMA*t*t));
        }

        float uxr[4], uyr[4], uzr[4];
        #pragma unroll
        for (int r4 = 0; r4 < 4; r4++){
            const int sl = q*4 + r4;
            uxr[r4] = __shfl(ux, sl, 16);
            uyr[r4] = __shfl(uy, sl, 16);
            uzr[r4] = __shfl(uz, sl, 16);
        }

        #pragma unroll
        for (int nt = 0; nt < 2; nt++){
            f32x4 c = {b1v[0][nt], b1v[0][nt], b1v[0][nt], b1v[0][nt]};
            c = mfma16(afrag, w1hi[0][nt], c);
            c = mfma16(afrag, w1lo[0][nt], c);
            s0a[nt] += fmaxf(c[0],0.f)+fmaxf(c[1],0.f)+fmaxf(c[2],0.f)+fmaxf(c[3],0.f);
        }
        #pragma unroll
        for (int nt = 0; nt < 2; nt++){
            f32x4 c = {b1v[1][nt], b1v[1][nt], b1v[1][nt], b1v[1][nt]};
            c = mfma16(afrag, w1hi[1][nt], c);
            c = mfma16(afrag, w1lo[1][nt], c);
            #pragma unroll
            for (int r4 = 0; r4 < 4; r4++){
                const float h = fmaxf(c[r4], 0.f);
                T[nt][0] = fmaf(h, uxr[r4], T[nt][0]);
                T[nt][1] = fmaf(h, uyr[r4], T[nt][1]);
                T[nt][2] = fmaf(h, uzr[r4], T[nt][2]);
            }
        }
    }

    // cross-quad reduce (rows live in quads)
    #pragma unroll
    for (int nt = 0; nt < 2; nt++){
        s0a[nt] += __shfl_down(s0a[nt], 32, 64);
        s0a[nt] += __shfl_down(s0a[nt], 16, 64);
        #pragma unroll
        for (int i = 0; i < 3; i++){
            T[nt][i] += __shfl_down(T[nt][i], 32, 64);
            T[nt][i] += __shfl_down(T[nt][i], 16, 64);
        }
    }
    #pragma unroll
    for (int off = 32; off > 0; off >>= 1){
        upx += __shfl_down(upx, off, 64);
        upy += __shfl_down(upy, off, 64);
        upz += __shfl_down(upz, off, 64);
    }
    if (lane < 16){
        sS0[wv][lane]      = s0a[0];
        sS0[wv][16 + lane] = s0a[1];
        #pragma unroll
        for (int i = 0; i < 3; i++){
            sT[wv][lane][i]      = T[0][i];
            sT[wv][16 + lane][i] = T[1][i];
        }
    }
    if (lane == 0){ sUp[wv][0] = upx; sUp[wv][1] = upy; sUp[wv][2] = upz; }
    __syncthreads();
    if (tid == 0){
        float o0 = 0.f;
        for (int j = 0; j < R; j++){
            const float S = sS0[0][j] + sS0[1][j] + sS0[2][j] + sS0[3][j];
            o0 = fmaf(S, W2[j], o0);
        }
        out0[a] = o0 + (float)NP * B2[0];
        for (int i = 0; i < 3; i++){
            float t = 0.f;
            for (int j = 0; j < R; j++){
                const float Tj = sT[0][j][i] + sT[1][j][i] + sT[2][j][i] + sT[3][j][i];
                t = fmaf(Tj, W2[R + j], t);
            }
            const float Ui = 0.25f * (sUp[0][i] + sUp[1][i] + sUp[2][i] + sUp[3][i]);
            out1[a*3+i] = t + B2[1] * Ui;
        }
    }
}

// ---------------------------------------------------------------------------
// Per-point layer-1 features. x0g[b][f] row-major; x1s SoA: x1s[i][b*C+f]
// (3 planes of NP*C) for coalesced per-lane loads in k_layer2.
// ---------------------------------------------------------------------------
__global__ __launch_bounds__(256) void k_point1(
    const float* __restrict__ out0, const float* __restrict__ out1,
    const float* __restrict__ si0_w, const float* __restrict__ si0_b,
    const float* __restrict__ si1_w, const float* __restrict__ nl_b,
    float* __restrict__ x0g, float* __restrict__ x1s)
{
    const int b = blockIdx.x*256 + threadIdx.x;
    if (b >= NP) return;
    const float o0 = out0[b];
    const float o1x = out1[b*3+0], o1y = out1[b*3+1], o1z = out1[b*3+2];
    #pragma unroll
    for (int g = 0; g < C; g++){
        x0g[b*C+g] = eluf(fmaf(o0, si0_w[g], si0_b[g]));
        const float w = si1_w[g];
        const float tx = o1x*w, ty = o1y*w, tz = o1z*w;
        const float n = sqrtf(fmaxf(tx*tx + ty*ty + tz*tz, 1e-8f));
        const float sc = eluf(n + nl_b[g]) / n;
        x1s[0*NP*C + b*C+g] = tx*sc;
        x1s[1*NP*C + b*C+g] = ty*sc;
        x1s[2*NP*C + b*C+g] = tz*sc;
    }
}

// ---------------------------------------------------------------------------
// Layer 2 (MFMA, BARRIER-FREE K-loop): block per 'a'; live filters 0 / 2 only
// (layer-2 degree-1 outputs are dead code). Per lane: own geometry (row l16),
// u for epilogue rows via width-16 shuffles, x0/ud loaded per-lane from
// global. H transpose is wave-private LDS (lgkmcnt only, no barrier).
// GEMM1 j-interleave: N-tile nt computes j = 2n+nt, so the C-layout pair
// (c0[r],c1[r]) packs into one conflict-free ds_write_b32.
// c00[a,f] = sum_b rad0(a,b,f)*x0[b,f]
// c10[a,f] = sum_b rad2(a,b,f)*dot(u(a,b), x1[b,f,:])
// ---------------------------------------------------------------------------
__global__ __launch_bounds__(256) void k_layer2(
    const float* __restrict__ points,
    const float* __restrict__ W1, const float* __restrict__ B1,
    const float* __restrict__ W2, const float* __restrict__ B2,
    const float* __restrict__ x0g, const float* __restrict__ x1s,
    float* __restrict__ c00, float* __restrict__ c10)
{
    __shared__ __align__(16) short sH[4][2][16*40];   // [wave][filter][row*40]
    __shared__ float sRed[4][2][16];

    const int tid  = threadIdx.x;
    const int lane = tid & 63;
    const int wv   = tid >> 6;
    const int l16  = lane & 15;
    const int q    = lane >> 4;
    const int a    = blockIdx.x;
    const float pax = points[a*3+0], pay = points[a*3+1], paz = points[a*3+2];

    bf16x8 w1hi[2][2], w1lo[2][2], w2hi[2], w2lo[2];
    float  b1v[2][2], b2v[2];
    #pragma unroll
    for (int fi = 0; fi < 2; fi++){
        const int fx = (fi == 0) ? 0 : 2;
        #pragma unroll
        for (int nt = 0; nt < 2; nt++){
            load_bfrag<R>(W1 + fx*R*R, q, 2*l16 + nt, w1hi[fi][nt], w1lo[fi][nt]);
            b1v[fi][nt] = B1[fx*R + 2*l16 + nt];
        }
        load_bfrag<C>(W2 + fx*R*C, q, l16, w2hi[fi], w2lo[fi]);
        b2v[fi] = B2[fx*C + l16];
    }

    float acc0 = 0.f, acc1 = 0.f;
    short* sH0 = sH[wv][0];
    short* sH1 = sH[wv][1];

    for (int bt = 0; bt < 16; bt++){
        const int bA = bt*64 + wv*16 + l16;
        const float rx = pax - points[bA*3+0];
        const float ry = pay - points[bA*3+1];
        const float rz = paz - points[bA*3+2];
        const float ss = rx*rx + ry*ry + rz*rz;
        const float dij = sqrtf(ss);
        const float inv = 1.0f / sqrtf(fmaxf(ss, 1e-8f));
        const float ux = rx*inv, uy = ry*inv, uz = rz*inv;  // ==0 on diagonal

        float uxr[4], uyr[4], uzr[4];
        #pragma unroll
        for (int r4 = 0; r4 < 4; r4++){
            const int sl = q*4 + r4;
            uxr[r4] = __shfl(ux, sl, 16);
            uyr[r4] = __shfl(uy, sl, 16);
            uzr[r4] = __shfl(uz, sl, 16);
        }

        // epilogue inputs: rows bE = bt*64+wv*16+q*4+r4, col f = l16
        const int rb = (bt*64 + wv*16 + q*4)*C + l16;
        float x0v[4], udv[4];
        #pragma unroll
        for (int r4 = 0; r4 < 4; r4++){
            x0v[r4] = x0g[rb + r4*C];
            const float v0 = x1s[0*NP*C + rb + r4*C];
            const float v1 = x1s[1*NP*C + rb + r4*C];
            const float v2 = x1s[2*NP*C + rb + r4*C];
            udv[r4] = uxr[r4]*v0 + uyr[r4]*v1 + uzr[r4]*v2;
        }

        bf16x8 afrag;
        #pragma unroll
        for (int jj = 0; jj < 8; jj++){
            const float t = dij - (float)(q*8+jj)*DC;
            afrag[jj] = tobf(__expf(-GAMMA*t*t));
        }

        // GEMM1 both filters -> packed bf16 H into wave-private LDS
        #pragma unroll
        for (int fi = 0; fi < 2; fi++){
            f32x4 c0 = {b1v[fi][0], b1v[fi][0], b1v[fi][0], b1v[fi][0]};
            c0 = mfma16(afrag, w1hi[fi][0], c0);
            c0 = mfma16(afrag, w1lo[fi][0], c0);
            f32x4 c1 = {b1v[fi][1], b1v[fi][1], b1v[fi][1], b1v[fi][1]};
            c1 = mfma16(afrag, w1hi[fi][1], c1);
            c1 = mfma16(afrag, w1lo[fi][1], c1);
            short* sHf = (fi == 0) ? sH0 : sH1;
            #pragma unroll
            for (int r4 = 0; r4 < 4; r4++){
                const unsigned p = pack2bf(fmaxf(c0[r4], 0.f), fmaxf(c1[r4], 0.f));
                *(unsigned*)&sHf[(q*4+r4)*40 + 2*l16] = p;   // j=2*l16 (lo), 2*l16+1 (hi)
            }
        }
        asm volatile("s_waitcnt lgkmcnt(0)" ::: "memory");   // wave-internal transpose
        #pragma unroll
        for (int fi = 0; fi < 2; fi++){
            const short* sHf = (fi == 0) ? sH0 : sH1;
            const bf16x8 hf = *(const bf16x8*)(sHf + l16*40 + q*8);
            f32x4 d = {0.f, 0.f, 0.f, 0.f};
            d = mfma16(hf, w2hi[fi], d);
            d = mfma16(hf, w2lo[fi], d);
            #pragma unroll
            for (int r4 = 0; r4 < 4; r4++){
                const float v = d[r4] + b2v[fi];
                if (fi == 0) acc0 = fmaf(v, x0v[r4], acc0);
                else         acc1 = fmaf(v, udv[r4], acc1);
            }
        }
    }

    acc0 += __shfl_down(acc0, 32, 64); acc0 += __shfl_down(acc0, 16, 64);
    acc1 += __shfl_down(acc1, 32, 64); acc1 += __shfl_down(acc1, 16, 64);
    if (lane < 16){ sRed[wv][0][lane] = acc0; sRed[wv][1][lane] = acc1; }
    __syncthreads();
    if (tid < 16)
        c00[a*C + tid] = sRed[0][0][tid] + sRed[1][0][tid] + sRed[2][0][tid] + sRed[3][0][tid];
    else if (tid < 32){
        const int f = tid - 16;
        c10[a*C + f] = sRed[0][1][f] + sRed[1][1][f] + sRed[2][1][f] + sRed[3][1][f];
    }
}

// ---------------------------------------------------------------------------
// Readout stage 1: per-point layer-2 degree-0 features + partial mean pool.
// ---------------------------------------------------------------------------
__global__ __launch_bounds__(256) void k_readout1(
    const float* __restrict__ c00, const float* __restrict__ c10,
    const float* __restrict__ si0_w, const float* __restrict__ si0_b,
    float* __restrict__ partial)
{
    __shared__ float sred[4*C];
    const int tid = threadIdx.x;
    const int a = blockIdx.x*256 + tid;
    float v00[C], v10[C];
    #pragma unroll
    for (int f = 0; f < C; f++){ v00[f] = c00[a*C+f]; v10[f] = c10[a*C+f]; }
    float xg[C];
    #pragma unroll
    for (int g = 0; g < C; g++){
        float s = si0_b[g];
        #pragma unroll
        for (int f = 0; f < C; f++) s = fmaf(v00[f], si0_w[g*2*C + f], s);
        #pragma unroll
        for (int f = 0; f < C; f++) s = fmaf(v10[f], si0_w[g*2*C + C + f], s);
        xg[g] = eluf(s);
    }
    #pragma unroll
    for (int off = 32; off > 0; off >>= 1){
        #pragma unroll
        for (int g = 0; g < C; g++) xg[g] += __shfl_down(xg[g], off, 64);
    }
    const int lane = tid & 63, wv = tid >> 6;
    if (lane == 0){
        #pragma unroll
        for (int g = 0; g < C; g++) sred[wv*C + g] = xg[g];
    }
    __syncthreads();
    if (tid < C)
        partial[blockIdx.x*C + tid] =
            sred[tid] + sred[C + tid] + sred[2*C + tid] + sred[3*C + tid];
}

__global__ void k_readout2(const float* __restrict__ partial,
                           const float* __restrict__ fc_w,
                           const float* __restrict__ fc_b,
                           float* __restrict__ out)
{
    const int o = threadIdx.x;
    if (o < 8){
        float s = fc_b[o];
        #pragma unroll
        for (int g = 0; g < C; g++){
            const float m = (partial[g] + partial[C+g] + partial[2*C+g] + partial[3*C+g])
                            * (1.0f / (float)NP);
            s = fmaf(m, fc_w[g*8 + o], s);
        }
        out[o] = s;
    }
}

extern "C" void kernel_launch(void* const* d_in, const int* in_sizes, int n_in,
                              void* d_out, int out_size, void* d_ws, size_t ws_size,
                              hipStream_t stream)
{
    (void)in_sizes; (void)n_in; (void)out_size; (void)ws_size;
    const float* points   = (const float*)d_in[0];
    const float* l1_W1    = (const float*)d_in[1];
    const float* l1_B1    = (const float*)d_in[2];
    const float* l1_W2    = (const float*)d_in[3];
    const float* l1_B2    = (const float*)d_in[4];
    const float* l1_si0_w = (const float*)d_in[5];
    const float* l1_si0_b = (const float*)d_in[6];
    const float* l1_si1_w = (const float*)d_in[7];
    const float* l1_nl_b  = (const float*)d_in[8];
    const float* l2_W1    = (const float*)d_in[9];
    const float* l2_B1    = (const float*)d_in[10];
    const float* l2_W2    = (const float*)d_in[11];
    const float* l2_B2    = (const float*)d_in[12];
    const float* l2_si0_w = (const float*)d_in[13];
    const float* l2_si0_b = (const float*)d_in[14];
    // d_in[15] l2_si1_w, d_in[16] l2_nl_b: dead code in the reference readout
    const float* fc_w     = (const float*)d_in[17];
    const float* fc_b     = (const float*)d_in[18];

    float* ws      = (float*)d_ws;
    float* out0    = ws;                    // NP
    float* out1    = out0 + NP;             // NP*3
    float* x0g     = out1 + NP*3;           // NP*C
    float* x1s     = x0g + NP*C;            // 3*NP*C (SoA planes)
    float* c00     = x1s + 3*NP*C;          // NP*C
    float* c10     = c00 + NP*C;            // NP*C
    float* partial = c10 + NP*C;            // 4*C

    k_layer1<<<NP, 256, 0, stream>>>(points, l1_W1, l1_B1, l1_W2, l1_B2, out0, out1);
    k_point1<<<NP/256, 256, 0, stream>>>(out0, out1, l1_si0_w, l1_si0_b, l1_si1_w, l1_nl_b, x0g, x1s);
    k_layer2<<<NP, 256, 0, stream>>>(points, l2_W1, l2_B1, l2_W2, l2_B2, x0g, x1s, c00, c10);
    k_readout1<<<NP/256, 256, 0, stream>>>(c00, c10, l2_si0_w, l2_si0_b, partial);
    k_readout2<<<1, 64, 0, stream>>>(partial, fc_w, fc_b, (float*)d_out);
}